// Round 6
// baseline (1838.783 us; speedup 1.0000x reference)
//
#include <hip/hip_runtime.h>
#include <math.h>

// Problem constants
// H=256, D_IN=22, T=384, 4H=1024, N_R=N_L=384, H1=1024, H2=512, H3=1024, RRI=2

typedef _Float16 half2_t __attribute__((ext_vector_type(2)));

__device__ __forceinline__ float fast_sig(float x) {
    float e = __expf(-x);
    return __builtin_amdgcn_rcpf(1.f + e);
}
__device__ __forceinline__ float fast_tanh(float x) {
    x = fminf(fmaxf(x, -30.f), 30.f);
    float e = __expf(2.f * x);
    return (e - 1.f) * __builtin_amdgcn_rcpf(e + 1.f);
}

// ---------------------------------------------------------------------------
// prep
// ---------------------------------------------------------------------------
__global__ __launch_bounds__(256) void prep_kernel(
    const float* __restrict__ bih0, const float* __restrict__ bhh0,
    const float* __restrict__ bih1, const float* __restrict__ bhh1,
    const float* __restrict__ W3,   const float* __restrict__ Wout,
    float* __restrict__ b0sum, float* __restrict__ b1sum,
    float* __restrict__ W3sum, float* __restrict__ woutT)
{
    int idx = blockIdx.x * 256 + threadIdx.x;
    int stride = gridDim.x * 256;
    if (idx < 2048) {
        b0sum[idx] = bih0[idx] + bhh0[idx];
        b1sum[idx] = bih1[idx] + bhh1[idx];
        woutT[idx] = Wout[(idx & 1) * 1024 + (idx >> 1)];
    }
    for (int i = idx; i < 1024 * 512; i += stride) {
        int n = i >> 9, k = i & 511;
        W3sum[i] = W3[n * 1024 + k] + W3[n * 1024 + 512 + k];
    }
}

// ---------------------------------------------------------------------------
// proj0
// ---------------------------------------------------------------------------
__global__ __launch_bounds__(256) void proj0_kernel(
    const float* __restrict__ v_r, const float* __restrict__ v_l,
    const float* __restrict__ Wih0, const float* __restrict__ b0sum,
    float* __restrict__ pre0)
{
    int t = blockIdx.x;
    int sd = blockIdx.y;            // seq*2 + dir
    int seq = sd >> 1, dir = sd & 1;
    const float* x = (seq ? v_l : v_r) + t * 22;
    __shared__ float sx[22];
    if (threadIdx.x < 22) sx[threadIdx.x] = x[threadIdx.x];
    __syncthreads();
#pragma unroll
    for (int q = 0; q < 4; ++q) {
        int o = q * 256 + threadIdx.x;
        const float* wr = Wih0 + (size_t)(dir * 1024 + o) * 22;
        float acc = b0sum[dir * 1024 + o];
#pragma unroll
        for (int d = 0; d < 22; ++d) acc += sx[d] * wr[d];
        pre0[((size_t)sd * 384 + t) * 1024 + o] = acc;
    }
}

// ---------------------------------------------------------------------------
// LSTM recurrence, v21: v15's PROVEN 4-WG fdot2 structure, TWO CHAINS PER WG
// (both sequences of one direction share Whh -> same 64 pinned weight regs).
//
// R5 post-mortem: v20 (MFMA, 2 WGs, 128-reg weight set) passed but VGPR=124
// proved the allocator spilled the fragments to scratch (the ~128-VGPR tier
// from R11-R14 is real; 256-reg tier unreachable). Weight STORAGE forces
// >=2048 threads/chain -> v15's 4x512 shape is optimal. v15's remaining cost
// is protocol latency (~1700 of 2900 cyc/step) -- pure lockstep wait.
// v21 hides it: each WG interleaves chain A=(seq_r,dir) and B=(seq_l,dir),
// half-step out of phase:
//   resolveA(tag s) | barrier | computeA+publishA(s+1) |
//   resolveB(tag s) | barrier | computeB+publishB(s+1)
// Each mailbox has the opposite chain's compute phase (~500-700 cyc) to
// propagate through L2 before its poll resolves -> first-try hits expected.
// Worst case (no hiding) == v15 per-chain speed. Per-chain protocol, fdot,
// butterfly, gates: v15-VERBATIM. Disjoint pub regions per chain; disjoint
// LDS buffers hh4[cix]. Poll issue points staggered: pktB issued after
// barrier#1 (drains under A-compute), pktA for s+1 issued after barrier#2
// (drains under B-compute, resolved next iteration).
// Grid 32: dir = b&7 (>=2 exit), w = b>>3 in [0,4). Group dir's 4 WGs all on
// XCD dir (b%8 round-robin) -> pub traffic L2-local. 8 active CUs.
// ---------------------------------------------------------------------------
__global__ __launch_bounds__(512) void lstm_rec_kernel(
    const float* __restrict__ Whh,   // [2][1024][256] fp32
    const float* __restrict__ pre,   // layer0: [(seq*2+dir)][384][1024]; layer1: [(seq*384+t)][2][1024]
    float* __restrict__ out,         // [2][384][512]  (cols: dir*256 + j)
    unsigned long long* pub,         // [4 chains][2 parity][128]
    int layer)
{
    const int b = blockIdx.x;
    const int dir = b & 7;                   // XCD id under %8 round-robin
    const int w = b >> 3;                    // 0..3
    if (dir >= 2) return;
    const int tid = threadIdx.x;
    const int ks = tid & 7;                  // 32-wide k-slice
    const int jloc = tid >> 3;               // 0..63
    const int jj = (w << 6) + jloc;          // own h index
    const int cA = dir;                      // chain (seq 0, dir)
    const int cB = 2 + dir;                  // chain (seq 1, dir)

    // h in LDS per chain: 8 segments of 16 half2, stride 5 float4 (4+1 pad).
    __shared__ __align__(16) float4 hh4[2][2][40];   // [chain][parity][...]

    // 64 pinned register weights (shared by both chains -- same Whh[dir]).
    float wA[64];
#pragma unroll
    for (int g = 0; g < 4; ++g) {
        const float* wr = Whh + (((size_t)(dir * 1024 + g * 256 + jj)) << 8) + (ks << 5);
#pragma unroll
        for (int q = 0; q < 16; ++q) {
            float2 v = *(const float2*)(wr + 2 * q);
            half2_t h2; h2.x = (_Float16)v.x; h2.y = (_Float16)v.y;
            wA[g * 16 + q] = __builtin_bit_cast(float, h2);
        }
    }
#pragma unroll
    for (int q = 0; q < 64; ++q) asm volatile("" : "+v"(wA[q]));

    ((float*)hh4)[tid] = 0.f;                // 640 floats total
    if (tid < 128) ((float*)hh4)[512 + tid] = 0.f;
    float cstA = 0.f, cstB = 0.f;            // redundant in 8 lanes, bit-identical

    // poll lane mapping (v15-verbatim): lanes ks in {6,7}, cid<96
    const int cid = (jloc << 1) | (ks & 1);
    const bool poller = (ks >= 6) && (cid < 96);
    int P = 0;
    const unsigned long long* srcA = nullptr;
    const unsigned long long* srcB = nullptr;
    if (poller) {
        int peer = cid >> 5, pr = cid & 31;
        int wp = (w + 1 + peer) & 3;
        P = (wp << 5) + pr;                  // peer global pair index
    }
    unsigned long long pktA = 0, pktB = 0;
    __syncthreads();

    for (int s = 0; s < 384; ++s) {
        const int t = dir ? (383 - s) : s;
        const float* preA = (layer == 0)
            ? pre + ((size_t)(0 * 2 + dir) * 384 + t) * 1024
            : pre + (((size_t)(0 * 384 + t)) * 2 + dir) * 1024;
        const float* preB = (layer == 0)
            ? pre + ((size_t)(1 * 2 + dir) * 384 + t) * 1024
            : pre + (((size_t)(1 * 384 + t)) * 2 + dir) * 1024;
        float pvA = (ks < 4) ? preA[(ks << 8) + jj] : 0.f;   // drain under fdot
        float pvB = (ks < 4) ? preB[(ks << 8) + jj] : 0.f;

        const int par = s & 1, pn = par ^ 1;

        // ---- resolve A poll (tag s): pktA issued end of previous iteration ----
        if (s > 0 && poller) {
            const unsigned long long* src =
                &pub[((size_t)cA * 2 + par) * 128 + P];
            if ((unsigned)(pktA >> 32) != (unsigned)s) {
                for (int it = 0; it < 65536; ++it) {
                    __builtin_amdgcn_s_sleep(1);
                    pktA = __hip_atomic_load(src, __ATOMIC_RELAXED, __HIP_MEMORY_SCOPE_AGENT);
                    if ((unsigned)(pktA >> 32) == (unsigned)s) break;
                }
            }
            ((half2_t*)&hh4[0][par][0])[(P >> 4) * 20 + (P & 15)] =
                __builtin_bit_cast(half2_t, (unsigned)pktA);
        }
        __syncthreads();                     // hh4[A][par] complete

        // issue B poll (tag s): B-peers published at end of previous
        // iteration; this load drains under A-compute (~500 cyc slack).
        if (s > 0 && poller)
            pktB = __hip_atomic_load(&pub[((size_t)cB * 2 + par) * 128 + P],
                                     __ATOMIC_RELAXED, __HIP_MEMORY_SCOPE_AGENT);

        // ---- chain A compute (v15-verbatim) ----
        {
            const float4* hb = &hh4[0][par][ks * 5];
            float4 hl0 = hb[0], hl1 = hb[1], hl2 = hb[2], hl3 = hb[3];
            const float4 hls[4] = {hl0, hl1, hl2, hl3};
            float a0 = 0.f, a1 = 0.f, a2 = 0.f, a3 = 0.f;
#pragma unroll
            for (int m = 0; m < 4; ++m) {
                const float he[4] = {hls[m].x, hls[m].y, hls[m].z, hls[m].w};
#pragma unroll
                for (int e = 0; e < 4; ++e) {
                    half2_t hv = __builtin_bit_cast(half2_t, he[e]);
                    int q = 4 * m + e;
                    a0 = __builtin_amdgcn_fdot2(__builtin_bit_cast(half2_t, wA[q]),      hv, a0, false);
                    a1 = __builtin_amdgcn_fdot2(__builtin_bit_cast(half2_t, wA[16 + q]), hv, a1, false);
                    a2 = __builtin_amdgcn_fdot2(__builtin_bit_cast(half2_t, wA[32 + q]), hv, a2, false);
                    a3 = __builtin_amdgcn_fdot2(__builtin_bit_cast(half2_t, wA[48 + q]), hv, a3, false);
                }
            }
            a0 += (ks == 0) ? pvA : 0.f;
            a1 += (ks == 1) ? pvA : 0.f;
            a2 += (ks == 2) ? pvA : 0.f;
            a3 += (ks == 3) ? pvA : 0.f;
#pragma unroll
            for (int d = 1; d < 8; d <<= 1) {
                a0 += __shfl_xor(a0, d);
                a1 += __shfl_xor(a1, d);
                a2 += __shfl_xor(a2, d);
                a3 += __shfl_xor(a3, d);
            }
            float iv = fast_sig(a0);
            float fv = fast_sig(a1);
            float gv = fast_tanh(a2);
            float ov = fast_sig(a3);
            cstA = fv * cstA + iv * gv;
            float h = ov * fast_tanh(cstA);

            unsigned hb16 = (unsigned)__builtin_bit_cast(unsigned short, (_Float16)h);
            unsigned nb = (unsigned)__shfl_xor((int)hb16, 8);   // partner jloc^1
            if (ks == 0) {
                ((unsigned short*)&hh4[0][pn][0])[(jj >> 5) * 40 + (jj & 31)] =
                    (unsigned short)hb16;
                if ((jloc & 1) == 0) {
                    unsigned payload = (hb16 & 0xffffu) | (nb << 16);
                    int Pw = (w << 5) + (jloc >> 1);
                    unsigned long long pk =
                        ((unsigned long long)(unsigned)(s + 1) << 32) | payload;
                    __hip_atomic_store(&pub[((size_t)cA * 2 + pn) * 128 + Pw], pk,
                                       __ATOMIC_RELAXED, __HIP_MEMORY_SCOPE_AGENT);
                }
            }
            if (ks == 1) {
                out[((size_t)0 * 384 + t) * 512 + dir * 256 + jj] = h;
            }
        }

        // ---- resolve B poll (tag s) ----
        if (s > 0 && poller) {
            const unsigned long long* src =
                &pub[((size_t)cB * 2 + par) * 128 + P];
            if ((unsigned)(pktB >> 32) != (unsigned)s) {
                for (int it = 0; it < 65536; ++it) {
                    __builtin_amdgcn_s_sleep(1);
                    pktB = __hip_atomic_load(src, __ATOMIC_RELAXED, __HIP_MEMORY_SCOPE_AGENT);
                    if ((unsigned)(pktB >> 32) == (unsigned)s) break;
                }
            }
            ((half2_t*)&hh4[1][par][0])[(P >> 4) * 20 + (P & 15)] =
                __builtin_bit_cast(half2_t, (unsigned)pktB);
        }
        __syncthreads();                     // hh4[B][par] complete; hh4[A][pn] own writes drained

        // issue A poll (tag s+1) for next iteration: A-peers publish s+1
        // during their A-phase (~now); resolved after our B-compute.
        if (poller)
            pktA = __hip_atomic_load(&pub[((size_t)cA * 2 + pn) * 128 + P],
                                     __ATOMIC_RELAXED, __HIP_MEMORY_SCOPE_AGENT);

        // ---- chain B compute (v15-verbatim) ----
        {
            const float4* hb = &hh4[1][par][ks * 5];
            float4 hl0 = hb[0], hl1 = hb[1], hl2 = hb[2], hl3 = hb[3];
            const float4 hls[4] = {hl0, hl1, hl2, hl3};
            float a0 = 0.f, a1 = 0.f, a2 = 0.f, a3 = 0.f;
#pragma unroll
            for (int m = 0; m < 4; ++m) {
                const float he[4] = {hls[m].x, hls[m].y, hls[m].z, hls[m].w};
#pragma unroll
                for (int e = 0; e < 4; ++e) {
                    half2_t hv = __builtin_bit_cast(half2_t, he[e]);
                    int q = 4 * m + e;
                    a0 = __builtin_amdgcn_fdot2(__builtin_bit_cast(half2_t, wA[q]),      hv, a0, false);
                    a1 = __builtin_amdgcn_fdot2(__builtin_bit_cast(half2_t, wA[16 + q]), hv, a1, false);
                    a2 = __builtin_amdgcn_fdot2(__builtin_bit_cast(half2_t, wA[32 + q]), hv, a2, false);
                    a3 = __builtin_amdgcn_fdot2(__builtin_bit_cast(half2_t, wA[48 + q]), hv, a3, false);
                }
            }
            a0 += (ks == 0) ? pvB : 0.f;
            a1 += (ks == 1) ? pvB : 0.f;
            a2 += (ks == 2) ? pvB : 0.f;
            a3 += (ks == 3) ? pvB : 0.f;
#pragma unroll
            for (int d = 1; d < 8; d <<= 1) {
                a0 += __shfl_xor(a0, d);
                a1 += __shfl_xor(a1, d);
                a2 += __shfl_xor(a2, d);
                a3 += __shfl_xor(a3, d);
            }
            float iv = fast_sig(a0);
            float fv = fast_sig(a1);
            float gv = fast_tanh(a2);
            float ov = fast_sig(a3);
            cstB = fv * cstB + iv * gv;
            float h = ov * fast_tanh(cstB);

            unsigned hb16 = (unsigned)__builtin_bit_cast(unsigned short, (_Float16)h);
            unsigned nb = (unsigned)__shfl_xor((int)hb16, 8);
            if (ks == 0) {
                ((unsigned short*)&hh4[1][pn][0])[(jj >> 5) * 40 + (jj & 31)] =
                    (unsigned short)hb16;
                if ((jloc & 1) == 0) {
                    unsigned payload = (hb16 & 0xffffu) | (nb << 16);
                    int Pw = (w << 5) + (jloc >> 1);
                    unsigned long long pk =
                        ((unsigned long long)(unsigned)(s + 1) << 32) | payload;
                    __hip_atomic_store(&pub[((size_t)cB * 2 + pn) * 128 + Pw], pk,
                                       __ATOMIC_RELAXED, __HIP_MEMORY_SCOPE_AGENT);
                }
            }
            if (ks == 1) {
                out[((size_t)1 * 384 + t) * 512 + dir * 256 + jj] = h;
            }
        }
        __syncthreads();                     // hh4[B][pn] own region complete
    }
}

// ---------------------------------------------------------------------------
// Generic NT GEMM: C[M][N] = act(scale * A[M][K] @ W[N][K]^T + bias[N])
// ---------------------------------------------------------------------------
__global__ __launch_bounds__(256) void gemm_nt_kernel(
    const float* __restrict__ A, const float* __restrict__ W,
    const float* __restrict__ bias, float* __restrict__ C,
    int M, int N, int K, float scale, int do_relu)
{
    __shared__ float As[32][68];
    __shared__ float Ws[32][68];
    const int tid = threadIdx.x;
    const int n0 = blockIdx.x * 64, m0 = blockIdx.y * 64;
    const int lr = tid >> 2;
    const int lk = (tid & 3) * 8;
    const int tm = tid >> 4, tn = tid & 15;
    float acc[4][4];
#pragma unroll
    for (int i = 0; i < 4; ++i)
#pragma unroll
        for (int j = 0; j < 4; ++j) acc[i][j] = 0.f;

    for (int kc = 0; kc < K; kc += 32) {
        float4 a0 = *(const float4*)(A + (size_t)(m0 + lr) * K + kc + lk);
        float4 a1 = *(const float4*)(A + (size_t)(m0 + lr) * K + kc + lk + 4);
        float4 w0 = *(const float4*)(W + (size_t)(n0 + lr) * K + kc + lk);
        float4 w1 = *(const float4*)(W + (size_t)(n0 + lr) * K + kc + lk + 4);
        __syncthreads();
        As[lk + 0][lr] = a0.x; As[lk + 1][lr] = a0.y; As[lk + 2][lr] = a0.z; As[lk + 3][lr] = a0.w;
        As[lk + 4][lr] = a1.x; As[lk + 5][lr] = a1.y; As[lk + 6][lr] = a1.z; As[lk + 7][lr] = a1.w;
        Ws[lk + 0][lr] = w0.x; Ws[lk + 1][lr] = w0.y; Ws[lk + 2][lr] = w0.z; Ws[lk + 3][lr] = w0.w;
        Ws[lk + 4][lr] = w1.x; Ws[lk + 5][lr] = w1.y; Ws[lk + 6][lr] = w1.z; Ws[lk + 7][lr] = w1.w;
        __syncthreads();
#pragma unroll
        for (int kk = 0; kk < 32; ++kk) {
            float4 av = *(const float4*)&As[kk][tm * 4];
            float4 wv = *(const float4*)&Ws[kk][tn * 4];
            acc[0][0] += av.x * wv.x; acc[0][1] += av.x * wv.y; acc[0][2] += av.x * wv.z; acc[0][3] += av.x * wv.w;
            acc[1][0] += av.y * wv.x; acc[1][1] += av.y * wv.y; acc[1][2] += av.y * wv.z; acc[1][3] += av.y * wv.w;
            acc[2][0] += av.z * wv.x; acc[2][1] += av.z * wv.y; acc[2][2] += av.z * wv.z; acc[2][3] += av.z * wv.w;
            acc[3][0] += av.w * wv.x; acc[3][1] += av.w * wv.y; acc[3][2] += av.w * wv.z; acc[3][3] += av.w * wv.w;
        }
    }
    float4 bv = make_float4(0.f, 0.f, 0.f, 0.f);
    if (bias) bv = *(const float4*)(bias + n0 + tn * 4);
#pragma unroll
    for (int i = 0; i < 4; ++i) {
        int m = m0 + tm * 4 + i;
        float4 v;
        v.x = scale * acc[i][0] + bv.x;
        v.y = scale * acc[i][1] + bv.y;
        v.z = scale * acc[i][2] + bv.z;
        v.w = scale * acc[i][3] + bv.w;
        if (do_relu) {
            v.x = fmaxf(v.x, 0.f); v.y = fmaxf(v.y, 0.f);
            v.z = fmaxf(v.z, 0.f); v.w = fmaxf(v.w, 0.f);
        }
        *(float4*)(C + (size_t)m * N + n0 + tn * 4) = v;
    }
}

// ---------------------------------------------------------------------------
// pairwise: out[i][j][:] = log_softmax( sum_c relu(ur'[i][c]+ul[j][c]) * woutT[c][:] + bout )
// ---------------------------------------------------------------------------
__global__ __launch_bounds__(256) void pairwise_kernel(
    const float* __restrict__ u,      // [768][1024]
    const float* __restrict__ woutT,  // [1024][2]
    const float* __restrict__ bout,   // [2]
    float* __restrict__ out)          // [384][384][2]
{
    __shared__ float Ur[32][132];
    __shared__ float Ul[32][132];
    __shared__ float Wo[256];
    const int tid = threadIdx.x;
    const int j0 = blockIdx.x * 32, i0 = blockIdx.y * 32;
    const int ii = tid >> 4, jj = tid & 15;
    const int il0 = ii, il1 = ii + 16;
    const int jl0 = jj, jl1 = jj + 16;
    float acc000 = 0.f, acc001 = 0.f, acc010 = 0.f, acc011 = 0.f;
    float acc100 = 0.f, acc101 = 0.f, acc110 = 0.f, acc111 = 0.f;
    const int lrw = tid >> 3;
    const int lcb = (tid & 7) * 16;

    for (int cc = 0; cc < 1024; cc += 128) {
        __syncthreads();
#pragma unroll
        for (int q = 0; q < 4; ++q) {
            *(float4*)&Ur[lrw][lcb + 4 * q] =
                *(const float4*)(u + (size_t)(i0 + lrw) * 1024 + cc + lcb + 4 * q);
            *(float4*)&Ul[lrw][lcb + 4 * q] =
                *(const float4*)(u + (size_t)(384 + j0 + lrw) * 1024 + cc + lcb + 4 * q);
        }
        if (tid < 128)
            *(float2*)&Wo[tid * 2] = *(const float2*)(woutT + (size_t)(cc + tid) * 2);
        __syncthreads();

        for (int c = 0; c < 128; c += 4) {
            float4 a0  = *(const float4*)&Ur[il0][c];
            float4 a1  = *(const float4*)&Ur[il1][c];
            float4 b0v = *(const float4*)&Ul[jl0][c];
            float4 b1v = *(const float4*)&Ul[jl1][c];
            float4 wA4 = *(const float4*)&Wo[c * 2];
            float4 wB4 = *(const float4*)&Wo[c * 2 + 4];
#define PW_STEP(AX, W0, W1)                                   \
            { float rr;                                       \
              rr = fmaxf(a0.AX + b0v.AX, 0.f); acc000 += rr*(W0); acc001 += rr*(W1); \
              rr = fmaxf(a0.AX + b1v.AX, 0.f); acc010 += rr*(W0); acc011 += rr*(W1); \
              rr = fmaxf(a1.AX + b0v.AX, 0.f); acc100 += rr*(W0); acc101 += rr*(W1); \
              rr = fmaxf(a1.AX + b1v.AX, 0.f); acc110 += rr*(W0); acc111 += rr*(W1); }
            PW_STEP(x, wA4.x, wA4.y)
            PW_STEP(y, wA4.z, wA4.w)
            PW_STEP(z, wB4.x, wB4.y)
            PW_STEP(w, wB4.z, wB4.w)
#undef PW_STEP
        }
    }
    float2 bo = *(const float2*)bout;
    float pa[2][2][2] = {{{acc000, acc001}, {acc010, acc011}},
                         {{acc100, acc101}, {acc110, acc111}}};
#pragma unroll
    for (int pi = 0; pi < 2; ++pi)
#pragma unroll
        for (int pj = 0; pj < 2; ++pj) {
            float l0 = pa[pi][pj][0] + bo.x;
            float l1 = pa[pi][pj][1] + bo.y;
            float m = fmaxf(l0, l1);
            float lse = m + logf(expf(l0 - m) + expf(l1 - m));
            int ig = i0 + ii + 16 * pi;
            int jg = j0 + jj + 16 * pj;
            float2 o2; o2.x = l0 - lse; o2.y = l1 - lse;
            *(float2*)(out + ((size_t)ig * 384 + jg) * 2) = o2;
        }
}

// ---------------------------------------------------------------------------
extern "C" void kernel_launch(void* const* d_in, const int* in_sizes, int n_in,
                              void* d_out, int out_size, void* d_ws, size_t ws_size,
                              hipStream_t stream)
{
    const float* v_r  = (const float*)d_in[0];
    const float* v_l  = (const float*)d_in[1];
    const float* Wih0 = (const float*)d_in[2];
    const float* Whh0 = (const float*)d_in[3];
    const float* bih0 = (const float*)d_in[4];
    const float* bhh0 = (const float*)d_in[5];
    const float* Wih1 = (const float*)d_in[6];
    const float* Whh1 = (const float*)d_in[7];
    const float* bih1 = (const float*)d_in[8];
    const float* bhh1 = (const float*)d_in[9];
    const float* W1   = (const float*)d_in[10];
    const float* b1   = (const float*)d_in[11];
    const float* W2   = (const float*)d_in[12];
    const float* b2   = (const float*)d_in[13];
    const float* W3   = (const float*)d_in[14];
    const float* b3   = (const float*)d_in[15];
    const float* Wout = (const float*)d_in[16];
    const float* bout = (const float*)d_in[17];
    float* out = (float*)d_out;

    float* ws = (float*)d_ws;
    size_t off = 0;
    float* b0sum = ws + off; off += 2048;
    float* b1sum = ws + off; off += 2048;
    float* W3sum = ws + off; off += 1024 * 512;
    float* woutT = ws + off; off += 2048;
    float* pre0  = ws + off; off += (size_t)4 * 384 * 1024;
    float* out0  = ws + off; off += (size_t)2 * 384 * 512;
    float* pre1  = ws + off; off += (size_t)768 * 2048;
    float* out1  = ws + off; off += (size_t)2 * 384 * 512;
    float* h1    = ws + off; off += (size_t)768 * 1024;
    float* h2    = ws + off; off += (size_t)768 * 512;
    float* u     = ws + off; off += (size_t)768 * 1024;
    unsigned long long* pub0 = (unsigned long long*)(ws + off); off += 4 * 2 * 128 * 2;
    unsigned long long* pub1 = (unsigned long long*)(ws + off); off += 4 * 2 * 128 * 2;

    prep_kernel<<<512, 256, 0, stream>>>(bih0, bhh0, bih1, bhh1, W3, Wout,
                                         b0sum, b1sum, W3sum, woutT);
    proj0_kernel<<<dim3(384, 4), 256, 0, stream>>>(v_r, v_l, Wih0, b0sum, pre0);
    lstm_rec_kernel<<<32, 512, 0, stream>>>(Whh0, pre0, out0, pub0, 0);
    gemm_nt_kernel<<<dim3(2048 / 64, 768 / 64), 256, 0, stream>>>(
        out0, Wih1, b1sum, pre1, 768, 2048, 512, 1.f, 0);
    lstm_rec_kernel<<<32, 512, 0, stream>>>(Whh1, pre1, out1, pub1, 1);
    gemm_nt_kernel<<<dim3(1024 / 64, 768 / 64), 256, 0, stream>>>(
        out1, W1, b1, h1, 768, 1024, 512, 1.f, 1);
    gemm_nt_kernel<<<dim3(512 / 64, 768 / 64), 256, 0, stream>>>(
        h1, W2, b2, h2, 768, 512, 1024, 1.f, 1);
    gemm_nt_kernel<<<dim3(1024 / 64, 384 / 64), 256, 0, stream>>>(
        h2, W3sum, b3, u, 384, 1024, 512, 0.5f, 0);
    gemm_nt_kernel<<<dim3(1024 / 64, 384 / 64), 256, 0, stream>>>(
        h2 + (size_t)384 * 512, W3sum, nullptr, u + (size_t)384 * 1024, 384, 1024, 512, 0.5f, 0);
    pairwise_kernel<<<dim3(12, 12), 256, 0, stream>>>(u, woutT, bout, out);
}

// Round 7
// 1440.669 us; speedup vs baseline: 1.2763x; 1.2763x over previous
//
#include <hip/hip_runtime.h>
#include <math.h>

// Problem constants
// H=256, D_IN=22, T=384, 4H=1024, N_R=N_L=384, H1=1024, H2=512, H3=1024, RRI=2

typedef _Float16 f16x8 __attribute__((ext_vector_type(8)));
typedef float f32x4 __attribute__((ext_vector_type(4)));

__device__ __forceinline__ float fast_sig(float x) {
    float e = __expf(-x);
    return __builtin_amdgcn_rcpf(1.f + e);
}
__device__ __forceinline__ float fast_tanh(float x) {
    x = fminf(fmaxf(x, -30.f), 30.f);
    float e = __expf(2.f * x);
    return (e - 1.f) * __builtin_amdgcn_rcpf(e + 1.f);
}

// ---------------------------------------------------------------------------
// prep
// ---------------------------------------------------------------------------
__global__ __launch_bounds__(256) void prep_kernel(
    const float* __restrict__ bih0, const float* __restrict__ bhh0,
    const float* __restrict__ bih1, const float* __restrict__ bhh1,
    const float* __restrict__ W3,   const float* __restrict__ Wout,
    float* __restrict__ b0sum, float* __restrict__ b1sum,
    float* __restrict__ W3sum, float* __restrict__ woutT)
{
    int idx = blockIdx.x * 256 + threadIdx.x;
    int stride = gridDim.x * 256;
    if (idx < 2048) {
        b0sum[idx] = bih0[idx] + bhh0[idx];
        b1sum[idx] = bih1[idx] + bhh1[idx];
        woutT[idx] = Wout[(idx & 1) * 1024 + (idx >> 1)];
    }
    for (int i = idx; i < 1024 * 512; i += stride) {
        int n = i >> 9, k = i & 511;
        W3sum[i] = W3[n * 1024 + k] + W3[n * 1024 + 512 + k];
    }
}

// ---------------------------------------------------------------------------
// proj0
// ---------------------------------------------------------------------------
__global__ __launch_bounds__(256) void proj0_kernel(
    const float* __restrict__ v_r, const float* __restrict__ v_l,
    const float* __restrict__ Wih0, const float* __restrict__ b0sum,
    float* __restrict__ pre0)
{
    int t = blockIdx.x;
    int sd = blockIdx.y;            // seq*2 + dir
    int seq = sd >> 1, dir = sd & 1;
    const float* x = (seq ? v_l : v_r) + t * 22;
    __shared__ float sx[22];
    if (threadIdx.x < 22) sx[threadIdx.x] = x[threadIdx.x];
    __syncthreads();
#pragma unroll
    for (int q = 0; q < 4; ++q) {
        int o = q * 256 + threadIdx.x;
        const float* wr = Wih0 + (size_t)(dir * 1024 + o) * 22;
        float acc = b0sum[dir * 1024 + o];
#pragma unroll
        for (int d = 0; d < 22; ++d) acc += sx[d] * wr[d];
        pre0[((size_t)sd * 384 + t) * 1024 + o] = acc;
    }
}

// ---------------------------------------------------------------------------
// LSTM recurrence, v22: v20 (PASSED, 605us) with the weight set pinned in
// AGPRs -- kills the scratch spill that dominated v20's step time.
//
// R6 post-mortem: v20's VGPR_Count=124 proved the allocator spilled the
// 128-reg wf[] to scratch (the ~128-VGPR allocator tier ignores
// __launch_bounds__ promises; restream ~500-800 cyc/step). gfx950's register
// file is UNIFIED (VGPR+AGPR, 512/lane) and MFMA reads A-operands directly
// from AGPRs (cdna4_isa §10). v22 stores wf as f32x4 (bit pattern of 8
// halves), pins into AGPRs with asm "+a", and issues steady-state MFMAs as
// inline asm: v_mfma_f32_16x16x32_f16 D(v), A(a), B(v), C=D(v). gfx950 MFMA
// has HW dependency interlocks -> raw asm chaining is safe. Arch VGPRs drop
// to ~80; 80V + 128A = 208 <= 256 budget at 2 waves/SIMD -> no spill.
// Everything else is v20-VERBATIM (probes, election, mailbox protocol with
// the R4 disjoint-slot fix, 3 barriers/step). v21's dual-chain interleave
// (787us + 32ms outlier) is discarded.
// ---------------------------------------------------------------------------
#define MFMA_AW(cf, wfr, bfr)                                              \
    asm("v_mfma_f32_16x16x32_f16 %0, %1, %2, %0"                           \
        : "+v"(cf) : "a"(wfr), "v"(bfr))

__global__ __launch_bounds__(512, 2) void lstm_rec_kernel(
    const float* __restrict__ Whh,   // [2][1024][256] fp32
    const float* __restrict__ pre,   // layer0: [(seq*2+dir)][384][1024]; layer1: [(seq*384+t)][2][1024]
    float* __restrict__ out,         // [2][384][512]  (cols: dir*256 + j)
    unsigned long long* pub,         // [4 chains][2 parity][128]
    int layer)
{
    const int b = blockIdx.x;
    const int chain = b & 7;                 // XCD id under %8 round-robin
    const int p = b >> 3;                    // j-half 0/1
    if (chain >= 4) return;
    const int seq = chain >> 1, dir = chain & 1;
    const int tid = threadIdx.x;
    const int w = tid >> 6;                  // wave 0..7
    const int l = tid & 63;
    const int lrow = l & 15;                 // loaded-row id within 16-tile
    const int kgrp = l >> 4;                 // k slot group 0..3

    __shared__ __align__(16) _Float16 hbuf[2][256];
    __shared__ __align__(16) float gsum[4][128];
    __shared__ int claim[8][16];

    // ---- k-pairing probe: perm[j] = h-offset (within 32-k tile) paired with
    //      this lane's A slot j. One-hot pa; pb marker; D lane/reg-uniform. ----
    int perm[8];
#pragma unroll
    for (int gs = 0; gs < 4; ++gs) {
#pragma unroll
        for (int js = 0; js < 8; ++js) {
            f16x8 pa, pb;
#pragma unroll
            for (int j = 0; j < 8; ++j) {
                pa[j] = (_Float16)((kgrp == gs && j == js) ? 1.f : 0.f);
                pb[j] = (_Float16)(float)(8 * kgrp + j);
            }
            f32x4 pc = {0.f, 0.f, 0.f, 0.f};
            pc = __builtin_amdgcn_mfma_f32_16x16x32_f16(pa, pb, pc, 0, 0, 0);
            if (gs == kgrp) perm[js] = (int)(pc[0] + 0.5f);
        }
    }

    // ---- row probe: lam[r] = loaded-row whose sum lands in reg r ----
    int lam[4];
    {
        f16x8 pa, pb;
#pragma unroll
        for (int j = 0; j < 8; ++j) { pa[j] = (_Float16)(float)lrow; pb[j] = (_Float16)1.f; }
        f32x4 pc = {0.f, 0.f, 0.f, 0.f};
        pc = __builtin_amdgcn_mfma_f32_16x16x32_f16(pa, pb, pc, 0, 0, 0);
#pragma unroll
        for (int r = 0; r < 4; ++r) lam[r] = (int)(pc[r] * 0.03125f + 0.5f);
    }
    // ---- election: one canonical writer per (wave, row) ----
    if (l < 16) claim[w][l] = -1;
    __syncthreads();
#pragma unroll
    for (int r = 0; r < 4; ++r) claim[w][lam[r]] = l;   // races OK, any winner
    __syncthreads();
    int mine = 0;
#pragma unroll
    for (int r = 0; r < 4; ++r) mine |= (claim[w][lam[r]] == l) ? (1 << r) : 0;

    // ---- weight prologue: 32 frags/lane (128 regs), perm applied, AGPR-pinned ----
    f32x4 wf[4][8];
    {
        const size_t nbase = (size_t)(dir * 1024 + p * 128 + 16 * w + lrow);
#pragma unroll
        for (int g = 0; g < 4; ++g) {
            const float* wr = Whh + (nbase + (size_t)g * 256) * 256;
#pragma unroll
            for (int c = 0; c < 8; ++c) {
                const int kt = (c < 4) ? (4 * p + c) : (4 * (1 - p) + (c - 4));
                f16x8 f;
#pragma unroll
                for (int j = 0; j < 8; ++j)
                    f[j] = (_Float16)wr[32 * kt + perm[j]];
                wf[g][c] = __builtin_bit_cast(f32x4, f);
            }
        }
    }
#pragma unroll
    for (int g = 0; g < 4; ++g)
#pragma unroll
        for (int c = 0; c < 8; ++c) asm volatile("" : "+a"(wf[g][c]));  // pin in AGPRs

    if (tid < 128) ((unsigned*)&hbuf[0][0])[tid] = 0u;   // h_{-1} = 0
    float cst = 0.f;
    const int jl = 16 * w + lrow;            // local j (used by lanes l<16)
    const int jglob = p * 128 + jl;
    const int peer_base = (1 - p) * 128;
    __syncthreads();

    for (int s = 0; s < 384; ++s) {
        const int t = dir ? (383 - s) : s;
        const float* pre_t = (layer == 0)
            ? pre + ((size_t)(seq * 2 + dir) * 384 + t) * 1024
            : pre + (((size_t)(seq * 384 + t)) * 2 + dir) * 1024;
        const int par = s & 1, pn = par ^ 1;

        // ---- issue peer poll + pre prefetch early; both drain under MFMAs ----
        const int q = 8 * w + (l & 7);       // peer pair id 0..63 (lanes l<8)
        const unsigned long long* psrc =
            pub + ((size_t)chain * 2 + par) * 128 + ((1 - p) << 6) + q;
        const bool do_poll = (s > 0) && (l < 8);
        unsigned long long pkt = 0;
        if (do_poll)
            pkt = __hip_atomic_load(psrc, __ATOMIC_RELAXED, __HIP_MEMORY_SCOPE_AGENT);

        float pg0 = 0.f, pg1 = 0.f, pg2 = 0.f, pg3 = 0.f;
        if (l < 16) {
            pg0 = pre_t[0 * 256 + jglob];
            pg1 = pre_t[1 * 256 + jglob];
            pg2 = pre_t[2 * 256 + jglob];
            pg3 = pre_t[3 * 256 + jglob];
        }

        f32x4 cf0 = {0.f, 0.f, 0.f, 0.f}, cf1 = {0.f, 0.f, 0.f, 0.f};
        f32x4 cf2 = {0.f, 0.f, 0.f, 0.f}, cf3 = {0.f, 0.f, 0.f, 0.f};

        // ---- own-half k-tiles (h this WG produced last step) ----
#pragma unroll
        for (int c = 0; c < 4; ++c) {
            const int kt = 4 * p + c;
            f32x4 bf = *(const f32x4*)((const char*)&hbuf[par][0] + (kt << 6) + (kgrp << 4));
            MFMA_AW(cf0, wf[0][c], bf);
            MFMA_AW(cf1, wf[1][c], bf);
            MFMA_AW(cf2, wf[2][c], bf);
            MFMA_AW(cf3, wf[3][c], bf);
        }

        // ---- resolve poll, write peer half of h_{s-1} into hbuf[par] ----
        if (do_poll) {
            if ((unsigned)(pkt >> 32) != (unsigned)s) {
                for (int it = 0; it < 65536; ++it) {
                    __builtin_amdgcn_s_sleep(1);
                    pkt = __hip_atomic_load(psrc, __ATOMIC_RELAXED, __HIP_MEMORY_SCOPE_AGENT);
                    if ((unsigned)(pkt >> 32) == (unsigned)s) break;
                }
            }
            *(unsigned*)&hbuf[par][peer_base + 2 * q] = (unsigned)pkt;
        }
        __syncthreads();                     // hbuf[par] peer half complete

        // ---- peer-half k-tiles ----
#pragma unroll
        for (int c = 4; c < 8; ++c) {
            const int kt = 4 * (1 - p) + (c - 4);
            f32x4 bf = *(const f32x4*)((const char*)&hbuf[par][0] + (kt << 6) + (kgrp << 4));
            MFMA_AW(cf0, wf[0][c], bf);
            MFMA_AW(cf1, wf[1][c], bf);
            MFMA_AW(cf2, wf[2][c], bf);
            MFMA_AW(cf3, wf[3][c], bf);
        }

        // ---- gsum scatter via probed lam[] (layout-independent) ----
#pragma unroll
        for (int r = 0; r < 4; ++r) {
            if (mine & (1 << r)) {
                const int idx = 16 * w + lam[r];
                gsum[0][idx] = cf0[r];
                gsum[1][idx] = cf1[r];
                gsum[2][idx] = cf2[r];
                gsum[3][idx] = cf3[r];
            }
        }
        __syncthreads();                     // gsum complete

        if (l < 16) {
            float a0 = gsum[0][jl] + pg0;
            float a1 = gsum[1][jl] + pg1;
            float a2 = gsum[2][jl] + pg2;
            float a3 = gsum[3][jl] + pg3;
            float iv = fast_sig(a0);
            float fv = fast_sig(a1);
            float gv = fast_tanh(a2);
            float ov = fast_sig(a3);
            cst = fv * cst + iv * gv;
            float h = ov * fast_tanh(cst);

            _Float16 h16 = (_Float16)h;
            hbuf[pn][jglob] = h16;                               // own half, next step
            out[((size_t)seq * 384 + t) * 512 + dir * 256 + jglob] = h;

            unsigned hb16 = (unsigned)__builtin_bit_cast(unsigned short, h16);
            unsigned nb = (unsigned)__shfl_xor((int)hb16, 1);    // partner jl^1
            if ((l & 1) == 0) {
                unsigned payload = (hb16 & 0xffffu) | (nb << 16);
                unsigned long long pk =
                    ((unsigned long long)(unsigned)(s + 1) << 32) | payload;
                __hip_atomic_store(
                    pub + ((size_t)chain * 2 + pn) * 128 + (p << 6) + (8 * w + (l >> 1)),
                    pk, __ATOMIC_RELAXED, __HIP_MEMORY_SCOPE_AGENT);
            }
        }
        __syncthreads();                     // hbuf[pn] own half ready for all waves
    }
}

// ---------------------------------------------------------------------------
// Generic NT GEMM: C[M][N] = act(scale * A[M][K] @ W[N][K]^T + bias[N])
// ---------------------------------------------------------------------------
__global__ __launch_bounds__(256) void gemm_nt_kernel(
    const float* __restrict__ A, const float* __restrict__ W,
    const float* __restrict__ bias, float* __restrict__ C,
    int M, int N, int K, float scale, int do_relu)
{
    __shared__ float As[32][68];
    __shared__ float Ws[32][68];
    const int tid = threadIdx.x;
    const int n0 = blockIdx.x * 64, m0 = blockIdx.y * 64;
    const int lr = tid >> 2;
    const int lk = (tid & 3) * 8;
    const int tm = tid >> 4, tn = tid & 15;
    float acc[4][4];
#pragma unroll
    for (int i = 0; i < 4; ++i)
#pragma unroll
        for (int j = 0; j < 4; ++j) acc[i][j] = 0.f;

    for (int kc = 0; kc < K; kc += 32) {
        float4 a0 = *(const float4*)(A + (size_t)(m0 + lr) * K + kc + lk);
        float4 a1 = *(const float4*)(A + (size_t)(m0 + lr) * K + kc + lk + 4);
        float4 w0 = *(const float4*)(W + (size_t)(n0 + lr) * K + kc + lk);
        float4 w1 = *(const float4*)(W + (size_t)(n0 + lr) * K + kc + lk + 4);
        __syncthreads();
        As[lk + 0][lr] = a0.x; As[lk + 1][lr] = a0.y; As[lk + 2][lr] = a0.z; As[lk + 3][lr] = a0.w;
        As[lk + 4][lr] = a1.x; As[lk + 5][lr] = a1.y; As[lk + 6][lr] = a1.z; As[lk + 7][lr] = a1.w;
        Ws[lk + 0][lr] = w0.x; Ws[lk + 1][lr] = w0.y; Ws[lk + 2][lr] = w0.z; Ws[lk + 3][lr] = w0.w;
        Ws[lk + 4][lr] = w1.x; Ws[lk + 5][lr] = w1.y; Ws[lk + 6][lr] = w1.z; Ws[lk + 7][lr] = w1.w;
        __syncthreads();
#pragma unroll
        for (int kk = 0; kk < 32; ++kk) {
            float4 av = *(const float4*)&As[kk][tm * 4];
            float4 wv = *(const float4*)&Ws[kk][tn * 4];
            acc[0][0] += av.x * wv.x; acc[0][1] += av.x * wv.y; acc[0][2] += av.x * wv.z; acc[0][3] += av.x * wv.w;
            acc[1][0] += av.y * wv.x; acc[1][1] += av.y * wv.y; acc[1][2] += av.y * wv.z; acc[1][3] += av.y * wv.w;
            acc[2][0] += av.z * wv.x; acc[2][1] += av.z * wv.y; acc[2][2] += av.z * wv.z; acc[2][3] += av.z * wv.w;
            acc[3][0] += av.w * wv.x; acc[3][1] += av.w * wv.y; acc[3][2] += av.w * wv.z; acc[3][3] += av.w * wv.w;
        }
    }
    float4 bv = make_float4(0.f, 0.f, 0.f, 0.f);
    if (bias) bv = *(const float4*)(bias + n0 + tn * 4);
#pragma unroll
    for (int i = 0; i < 4; ++i) {
        int m = m0 + tm * 4 + i;
        float4 v;
        v.x = scale * acc[i][0] + bv.x;
        v.y = scale * acc[i][1] + bv.y;
        v.z = scale * acc[i][2] + bv.z;
        v.w = scale * acc[i][3] + bv.w;
        if (do_relu) {
            v.x = fmaxf(v.x, 0.f); v.y = fmaxf(v.y, 0.f);
            v.z = fmaxf(v.z, 0.f); v.w = fmaxf(v.w, 0.f);
        }
        *(float4*)(C + (size_t)m * N + n0 + tn * 4) = v;
    }
}

// ---------------------------------------------------------------------------
// pairwise: out[i][j][:] = log_softmax( sum_c relu(ur'[i][c]+ul[j][c]) * woutT[c][:] + bout )
// ---------------------------------------------------------------------------
__global__ __launch_bounds__(256) void pairwise_kernel(
    const float* __restrict__ u,      // [768][1024]
    const float* __restrict__ woutT,  // [1024][2]
    const float* __restrict__ bout,   // [2]
    float* __restrict__ out)          // [384][384][2]
{
    __shared__ float Ur[32][132];
    __shared__ float Ul[32][132];
    __shared__ float Wo[256];
    const int tid = threadIdx.x;
    const int j0 = blockIdx.x * 32, i0 = blockIdx.y * 32;
    const int ii = tid >> 4, jj = tid & 15;
    const int il0 = ii, il1 = ii + 16;
    const int jl0 = jj, jl1 = jj + 16;
    float acc000 = 0.f, acc001 = 0.f, acc010 = 0.f, acc011 = 0.f;
    float acc100 = 0.f, acc101 = 0.f, acc110 = 0.f, acc111 = 0.f;
    const int lrw = tid >> 3;
    const int lcb = (tid & 7) * 16;

    for (int cc = 0; cc < 1024; cc += 128) {
        __syncthreads();
#pragma unroll
        for (int q = 0; q < 4; ++q) {
            *(float4*)&Ur[lrw][lcb + 4 * q] =
                *(const float4*)(u + (size_t)(i0 + lrw) * 1024 + cc + lcb + 4 * q);
            *(float4*)&Ul[lrw][lcb + 4 * q] =
                *(const float4*)(u + (size_t)(384 + j0 + lrw) * 1024 + cc + lcb + 4 * q);
        }
        if (tid < 128)
            *(float2*)&Wo[tid * 2] = *(const float2*)(woutT + (size_t)(cc + tid) * 2);
        __syncthreads();

        for (int c = 0; c < 128; c += 4) {
            float4 a0  = *(const float4*)&Ur[il0][c];
            float4 a1  = *(const float4*)&Ur[il1][c];
            float4 b0v = *(const float4*)&Ul[jl0][c];
            float4 b1v = *(const float4*)&Ul[jl1][c];
            float4 wA4 = *(const float4*)&Wo[c * 2];
            float4 wB4 = *(const float4*)&Wo[c * 2 + 4];
#define PW_STEP(AX, W0, W1)                                   \
            { float rr;                                       \
              rr = fmaxf(a0.AX + b0v.AX, 0.f); acc000 += rr*(W0); acc001 += rr*(W1); \
              rr = fmaxf(a0.AX + b1v.AX, 0.f); acc010 += rr*(W0); acc011 += rr*(W1); \
              rr = fmaxf(a1.AX + b0v.AX, 0.f); acc100 += rr*(W0); acc101 += rr*(W1); \
              rr = fmaxf(a1.AX + b1v.AX, 0.f); acc110 += rr*(W0); acc111 += rr*(W1); }
            PW_STEP(x, wA4.x, wA4.y)
            PW_STEP(y, wA4.z, wA4.w)
            PW_STEP(z, wB4.x, wB4.y)
            PW_STEP(w, wB4.z, wB4.w)
#undef PW_STEP
        }
    }
    float2 bo = *(const float2*)bout;
    float pa[2][2][2] = {{{acc000, acc001}, {acc010, acc011}},
                         {{acc100, acc101}, {acc110, acc111}}};
#pragma unroll
    for (int pi = 0; pi < 2; ++pi)
#pragma unroll
        for (int pj = 0; pj < 2; ++pj) {
            float l0 = pa[pi][pj][0] + bo.x;
            float l1 = pa[pi][pj][1] + bo.y;
            float m = fmaxf(l0, l1);
            float lse = m + logf(expf(l0 - m) + expf(l1 - m));
            int ig = i0 + ii + 16 * pi;
            int jg = j0 + jj + 16 * pj;
            float2 o2; o2.x = l0 - lse; o2.y = l1 - lse;
            *(float2*)(out + ((size_t)ig * 384 + jg) * 2) = o2;
        }
}

// ---------------------------------------------------------------------------
extern "C" void kernel_launch(void* const* d_in, const int* in_sizes, int n_in,
                              void* d_out, int out_size, void* d_ws, size_t ws_size,
                              hipStream_t stream)
{
    const float* v_r  = (const float*)d_in[0];
    const float* v_l  = (const float*)d_in[1];
    const float* Wih0 = (const float*)d_in[2];
    const float* Whh0 = (const float*)d_in[3];
    const float* bih0 = (const float*)d_in[4];
    const float* bhh0 = (const float*)d_in[5];
    const float* Wih1 = (const float*)d_in[6];
    const float* Whh1 = (const float*)d_in[7];
    const float* bih1 = (const float*)d_in[8];
    const float* bhh1 = (const float*)d_in[9];
    const float* W1   = (const float*)d_in[10];
    const float* b1   = (const float*)d_in[11];
    const float* W2   = (const float*)d_in[12];
    const float* b2   = (const float*)d_in[13];
    const float* W3   = (const float*)d_in[14];
    const float* b3   = (const float*)d_in[15];
    const float* Wout = (const float*)d_in[16];
    const float* bout = (const float*)d_in[17];
    float* out = (float*)d_out;

    float* ws = (float*)d_ws;
    size_t off = 0;
    float* b0sum = ws + off; off += 2048;
    float* b1sum = ws + off; off += 2048;
    float* W3sum = ws + off; off += 1024 * 512;
    float* woutT = ws + off; off += 2048;
    float* pre0  = ws + off; off += (size_t)4 * 384 * 1024;
    float* out0  = ws + off; off += (size_t)2 * 384 * 512;
    float* pre1  = ws + off; off += (size_t)768 * 2048;
    float* out1  = ws + off; off += (size_t)2 * 384 * 512;
    float* h1    = ws + off; off += (size_t)768 * 1024;
    float* h2    = ws + off; off += (size_t)768 * 512;
    float* u     = ws + off; off += (size_t)768 * 1024;
    unsigned long long* pub0 = (unsigned long long*)(ws + off); off += 4 * 2 * 128 * 2;
    unsigned long long* pub1 = (unsigned long long*)(ws + off); off += 4 * 2 * 128 * 2;

    prep_kernel<<<512, 256, 0, stream>>>(bih0, bhh0, bih1, bhh1, W3, Wout,
                                         b0sum, b1sum, W3sum, woutT);
    proj0_kernel<<<dim3(384, 4), 256, 0, stream>>>(v_r, v_l, Wih0, b0sum, pre0);
    lstm_rec_kernel<<<16, 512, 0, stream>>>(Whh0, pre0, out0, pub0, 0);
    gemm_nt_kernel<<<dim3(2048 / 64, 768 / 64), 256, 0, stream>>>(
        out0, Wih1, b1sum, pre1, 768, 2048, 512, 1.f, 0);
    lstm_rec_kernel<<<16, 512, 0, stream>>>(Whh1, pre1, out1, pub1, 1);
    gemm_nt_kernel<<<dim3(1024 / 64, 768 / 64), 256, 0, stream>>>(
        out1, W1, b1, h1, 768, 1024, 512, 1.f, 1);
    gemm_nt_kernel<<<dim3(512 / 64, 768 / 64), 256, 0, stream>>>(
        h1, W2, b2, h2, 768, 512, 1024, 1.f, 1);
    gemm_nt_kernel<<<dim3(1024 / 64, 384 / 64), 256, 0, stream>>>(
        h2, W3sum, b3, u, 384, 1024, 512, 0.5f, 0);
    gemm_nt_kernel<<<dim3(1024 / 64, 384 / 64), 256, 0, stream>>>(
        h2 + (size_t)384 * 512, W3sum, nullptr, u + (size_t)384 * 1024, 384, 1024, 512, 0.5f, 0);
    pairwise_kernel<<<dim3(12, 12), 256, 0, stream>>>(u, woutT, bout, out);
}